// Round 2
// baseline (675.902 us; speedup 1.0000x reference)
//
#include <hip/hip_runtime.h>

#define D_IN   256
#define HID    256
#define NNODES 100000
#define NEDGE  262144
#define NGROUPS 6250        // 100000 / 16 rows per MFMA m-group (exact)
#define GBLK   128          // blocks per z (x2 z = 256 blocks = 1/CU)
#define GW     8            // waves per block (512 threads)
#define GSTRIDE (GBLK * GW) // 1024 waves per z

typedef short short8            __attribute__((ext_vector_type(8)));
typedef float float4v           __attribute__((ext_vector_type(4)));
typedef unsigned short ushort8  __attribute__((ext_vector_type(8)));

__device__ __forceinline__ unsigned short f32_to_bf16_rne(float f) {
    unsigned int u = __float_as_uint(f);
    unsigned int r = u + 0x7FFFu + ((u >> 16) & 1u);
    return (unsigned short)(r >> 16);
}
__device__ __forceinline__ float bf16_to_f32(unsigned short h) {
    return __uint_as_float(((unsigned int)h) << 16);
}

// -------- W1 (fp32 [2*256][256], k-major) -> Wt (bf16 [z][n][k]) — LDS tile transpose --------
__global__ __launch_bounds__(256) void convert_w(
    const float* __restrict__ W1, unsigned short* __restrict__ Wt)
{
    __shared__ float tile[64][65];
    const int z = blockIdx.z, kb = blockIdx.x * 64, nb = blockIdx.y * 64;
    const int t = threadIdx.x;
    const int g = t >> 6, c = t & 63;
#pragma unroll
    for (int r = 0; r < 16; r++) {
        int kl = g * 16 + r;
        tile[kl][c] = W1[((size_t)(z * 256 + kb + kl)) * 256 + nb + c];
    }
    __syncthreads();
#pragma unroll
    for (int r = 0; r < 16; r++) {
        int nl = g * 16 + r;
        Wt[((size_t)(z * 256 + nb + nl)) * 256 + kb + c] = f32_to_bf16_rne(tile[c][nl]);
    }
}

// -------- Phase 1: U = Xsrc@W1_top + b1 (bf16), V = Xdst@W1_bot (bf16) --------
// Round-5 structure: B resident in LDS (128 KiB, XOR-swizzled), ONE barrier.
// LESSON (round-4, 105us): per-kk 1-deep A-prefetch exposes ~550 cyc latency
// 8x per group; 16 identically-cadenced waves phase-lock -> all pipes <40%.
// Fix is ILP not TLP: batch the ENTIRE group's A (16 dwordx4 -> 64 VGPR),
// double-buffered across groups: convert g's A (loaded one full group ago,
// latency fully covered) -> issue ALL of g+1's loads -> pure LDS+MFMA section
// (~2000 cyc >> 900 cyc latency) -> store. 512-thr block (8 waves, 2/SIMD,
// <=256 VGPR budget) to fit acc64+A64+af32 ~ 180 VGPRs without spill.
__global__ __launch_bounds__(512, 2) void gemm_xw_mfma(
    const float* __restrict__ Xsrc, const float* __restrict__ Xdst,
    const unsigned short* __restrict__ Wt, const float* __restrict__ b1,
    unsigned short* __restrict__ U, unsigned short* __restrict__ V)
{
    const int zz = blockIdx.z;
    const float* X = zz ? Xdst : Xsrc;
    const unsigned short* Wz = Wt + (size_t)zz * 256 * 256;
    unsigned short* C = zz ? V : U;

    __shared__ __align__(16) unsigned short Bs[256 * 256];   // 128 KiB

    const int t = threadIdx.x;
    // Stage B once: 8192 16B-chunks / 512 threads = 16 each.
#pragma unroll
    for (int i = 0; i < 16; i++) {
        int s = t + (i << 9);
        int n = s >> 5, c = s & 31;
        *(int4*)(Bs + n * 256 + ((c ^ (n & 7)) << 3)) =
            *(const int4*)(Wz + (size_t)n * 256 + (c << 3));
    }
    __syncthreads();        // the only barrier in this kernel

    const int w = t >> 6, lane = t & 63;
    const int quad = lane >> 4, l16 = lane & 15;
    const int r7 = l16 & 7;
    const unsigned short* Bl = Bs + l16 * 256;

    const int wid = w * GBLK + blockIdx.x;   // wave-major remainder spread

    float4 A[16];           // whole-group A panel, fp32 (64 VGPRs)
    int g = wid;
    if (g < NGROUPS) {
        const float* Ap = X + ((size_t)((g << 4) + l16)) * D_IN + (quad << 3);
#pragma unroll
        for (int kk = 0; kk < 8; kk++) {
            A[2 * kk]     = *(const float4*)(Ap + kk * 32);
            A[2 * kk + 1] = *(const float4*)(Ap + kk * 32 + 4);
        }
    }

    for (; g < NGROUPS; g += GSTRIDE) {
        // 1) Convert current group's A -> bf16 fragments (loads long complete).
        short8 af[8];
#pragma unroll
        for (int kk = 0; kk < 8; kk++) {
            float4 a0 = A[2 * kk], a1 = A[2 * kk + 1];
            af[kk][0] = (short)f32_to_bf16_rne(a0.x);
            af[kk][1] = (short)f32_to_bf16_rne(a0.y);
            af[kk][2] = (short)f32_to_bf16_rne(a0.z);
            af[kk][3] = (short)f32_to_bf16_rne(a0.w);
            af[kk][4] = (short)f32_to_bf16_rne(a1.x);
            af[kk][5] = (short)f32_to_bf16_rne(a1.y);
            af[kk][6] = (short)f32_to_bf16_rne(a1.z);
            af[kk][7] = (short)f32_to_bf16_rne(a1.w);
        }
        // 2) Issue next group's 16 loads NOW — hidden under the MFMA section.
        const int gn = g + GSTRIDE;
        if (gn < NGROUPS) {
            const float* Ap = X + ((size_t)((gn << 4) + l16)) * D_IN + (quad << 3);
#pragma unroll
            for (int kk = 0; kk < 8; kk++) {
                A[2 * kk]     = *(const float4*)(Ap + kk * 32);
                A[2 * kk + 1] = *(const float4*)(Ap + kk * 32 + 4);
            }
        }
        // 3) Pure LDS+MFMA section (no VMEM dependencies).
        float4v acc[16];
#pragma unroll
        for (int i = 0; i < 16; i++) acc[i] = (float4v){0.f, 0.f, 0.f, 0.f};
#pragma unroll
        for (int kk = 0; kk < 8; kk++) {
            const int cs = (((kk << 2) + quad) ^ r7) << 3;
#pragma unroll
            for (int tt = 0; tt < 16; tt++) {
                short8 bf = *(const short8*)(Bl + tt * 4096 + cs);
                // swapped operands: D = (Wt-tile) x (X-tile): lane owns output
                // ROW m = l16; output cols n = tt*16 + quad*4 + r.
                acc[tt] = __builtin_amdgcn_mfma_f32_16x16x32_bf16(bf, af[kk], acc[tt], 0, 0, 0);
            }
        }
        // 4) Epilogue: lane writes its own row: 16 x 8B stores, 32B/row/instr.
        const int row = (g << 4) + l16;
        unsigned short* Crow = C + (size_t)row * HID + (quad << 2);
#pragma unroll
        for (int tt = 0; tt < 16; tt++) {
            float4v a = acc[tt];
            if (zz == 0) {
                float4 bb = *(const float4*)(b1 + tt * 16 + (quad << 2));
                a[0] += bb.x; a[1] += bb.y; a[2] += bb.z; a[3] += bb.w;
            }
            ushort4 pk;
            pk.x = f32_to_bf16_rne(a[0]);
            pk.y = f32_to_bf16_rne(a[1]);
            pk.z = f32_to_bf16_rne(a[2]);
            pk.w = f32_to_bf16_rne(a[3]);
            *(ushort4*)(Crow + tt * 16) = pk;
        }
    }
}

// -------- Phase 2: out[e] = relu(U[s]+V[d]) . W2 + b2   (b1 folded into U) --------
__global__ __launch_bounds__(256) void edge_score_bf16(
    const unsigned short* __restrict__ U, const unsigned short* __restrict__ V,
    const float* __restrict__ W2, const float* __restrict__ b2,
    const int* __restrict__ epos, const int* __restrict__ eneg,
    float* __restrict__ out)
{
    const int w = threadIdx.x >> 6, lane = threadIdx.x & 63;
    const int half = lane >> 5, hl = lane & 31;
    const int ebase = blockIdx.x * 64 + w * 16;     // 16 edges per wave

    const int* ei = (ebase < NEDGE) ? epos : eneg;
    const int eb2 = (ebase < NEDGE) ? ebase : ebase - NEDGE;

    int sidx[8], didx[8];
#pragma unroll
    for (int p = 0; p < 8; p++) {
        int e = eb2 + 2 * p + half;
        sidx[p] = ei[e];
        didx[p] = ei[NEDGE + e];
    }
    ushort8 uu[8], vv[8];
#pragma unroll
    for (int p = 0; p < 8; p++)
        uu[p] = *(const ushort8*)(U + (size_t)sidx[p] * HID + hl * 8);
#pragma unroll
    for (int p = 0; p < 8; p++)
        vv[p] = *(const ushort8*)(V + (size_t)didx[p] * HID + hl * 8);

    float w2r[8];
    *(float4*)&w2r[0] = *(const float4*)(W2 + hl * 8);
    *(float4*)&w2r[4] = *(const float4*)(W2 + hl * 8 + 4);
    const float bb2 = b2[0];

#pragma unroll
    for (int p = 0; p < 8; p++) {
        float s = 0.f;
#pragma unroll
        for (int q = 0; q < 8; q++)
            s += fmaxf(bf16_to_f32(uu[p][q]) + bf16_to_f32(vv[p][q]), 0.f) * w2r[q];
#pragma unroll
        for (int off = 16; off; off >>= 1)     // xor within each 32-lane half
            s += __shfl_xor(s, off, 64);
        if (hl == 0) out[ebase + 2 * p + half] = s + bb2;
    }
}

// -------- Fallback (ws too small): direct per-edge MLP --------
__global__ __launch_bounds__(256) void edge_score_direct(
    const float* __restrict__ xs_, const float* __restrict__ xd_,
    const float* __restrict__ W1, const float* __restrict__ b1,
    const float* __restrict__ W2, const float* __restrict__ b2,
    const int* __restrict__ epos, const int* __restrict__ eneg,
    float* __restrict__ out)
{
    __shared__ float xrow[2 * D_IN];
    __shared__ float red[256];
    const int e = blockIdx.x;
    const int* ei = (e < NEDGE) ? epos : eneg;
    const int e2  = (e < NEDGE) ? e : e - NEDGE;
    const int s = ei[e2];
    const int d = ei[NEDGE + e2];
    const int t = threadIdx.x;

    xrow[t]        = xs_[(size_t)s * D_IN + t];
    xrow[D_IN + t] = xd_[(size_t)d * D_IN + t];
    __syncthreads();

    float acc = b1[t];
    for (int k = 0; k < 2 * D_IN; k++)
        acc += xrow[k] * W1[(size_t)k * HID + t];
    acc = fmaxf(acc, 0.f);
    red[t] = acc * W2[t];
    __syncthreads();
    for (int st = 128; st; st >>= 1) {
        if (t < st) red[t] += red[t + st];
        __syncthreads();
    }
    if (t == 0) out[e] = red[0] + b2[0];
}

extern "C" void kernel_launch(void* const* d_in, const int* in_sizes, int n_in,
                              void* d_out, int out_size, void* d_ws, size_t ws_size,
                              hipStream_t stream) {
    const float* x_src = (const float*)d_in[0];
    const float* x_dst = (const float*)d_in[1];
    const float* W1    = (const float*)d_in[2];
    const float* b1    = (const float*)d_in[3];
    const float* W2    = (const float*)d_in[4];
    const float* b2    = (const float*)d_in[5];
    const int*   epos  = (const int*)d_in[6];
    const int*   eneg  = (const int*)d_in[7];
    float* out = (float*)d_out;

    const size_t uv   = (size_t)NNODES * HID;
    const size_t need = (2 * uv + 2 * 256 * 256) * sizeof(unsigned short);
    if (ws_size >= need) {
        unsigned short* U  = (unsigned short*)d_ws;
        unsigned short* V  = U + uv;
        unsigned short* Wt = V + uv;
        convert_w<<<dim3(4, 4, 2), 256, 0, stream>>>(W1, Wt);
        gemm_xw_mfma<<<dim3(GBLK, 1, 2), 512, 0, stream>>>(x_src, x_dst, Wt, b1, U, V);
        edge_score_bf16<<<(2 * NEDGE) / 64, 256, 0, stream>>>(U, V, W2, b2, epos, eneg, out);
    } else {
        edge_score_direct<<<2 * NEDGE, 256, 0, stream>>>(x_src, x_dst, W1, b1, W2, b2, epos, eneg, out);
    }
}

// Round 3
// 655.165 us; speedup vs baseline: 1.0317x; 1.0317x over previous
//
#include <hip/hip_runtime.h>

#define D_IN   256
#define HID    256
#define NNODES 100000
#define NEDGE  262144
#define NGROUPS 6250        // 100000 / 16 rows per MFMA m-group (exact)
#define GBLK   128          // blocks per z (x2 z = 256 blocks = 1/CU)
#define GW     8            // waves per block (512 threads)
#define GSTRIDE (GBLK * GW) // 1024 waves per z

typedef short short8            __attribute__((ext_vector_type(8)));
typedef float float4v           __attribute__((ext_vector_type(4)));
typedef unsigned short ushort8  __attribute__((ext_vector_type(8)));

__device__ __forceinline__ unsigned short f32_to_bf16_rne(float f) {
    unsigned int u = __float_as_uint(f);
    unsigned int r = u + 0x7FFFu + ((u >> 16) & 1u);
    return (unsigned short)(r >> 16);
}
__device__ __forceinline__ float bf16_to_f32(unsigned short h) {
    return __uint_as_float(((unsigned int)h) << 16);
}

// -------- W1 (fp32 [2*256][256], k-major) -> Wt (bf16 [z][n][k]) — LDS tile transpose --------
__global__ __launch_bounds__(256) void convert_w(
    const float* __restrict__ W1, unsigned short* __restrict__ Wt)
{
    __shared__ float tile[64][65];
    const int z = blockIdx.z, kb = blockIdx.x * 64, nb = blockIdx.y * 64;
    const int t = threadIdx.x;
    const int g = t >> 6, c = t & 63;
#pragma unroll
    for (int r = 0; r < 16; r++) {
        int kl = g * 16 + r;
        tile[kl][c] = W1[((size_t)(z * 256 + kb + kl)) * 256 + nb + c];
    }
    __syncthreads();
#pragma unroll
    for (int r = 0; r < 16; r++) {
        int nl = g * 16 + r;
        Wt[((size_t)(z * 256 + nb + nl)) * 256 + kb + c] = f32_to_bf16_rne(tile[c][nl]);
    }
}

// -------- Phase 1: U = Xsrc@W1_top + b1 (bf16), V = Xdst@W1_bot (bf16) --------
// Round-6 structure: B resident in LDS (128 KiB, XOR-swizzled), ONE barrier.
// LESSON (round-4, 105us): 1-deep kk prefetch exposes ~550cyc latency 8x/group.
// LESSON (round-5, 465us!): whole-group A panel (A16+af8+acc16 ~ 200 regs)
// under a 128-VGPR launch_bounds cap -> ~75 regs spilled/iter -> 940 MB scratch
// traffic (FETCH 810MB). Fix: SAME prefetch distance (4 kk-blocks ~ 1000-2000
// cyc >> 900cyc HBM latency), 1/3 the registers: 4-slot rolling ring (8 float4
// = 32 regs). Per kk: convert slot kk&3 -> issue load for kk+4 (this group's
// 2nd half / next group's 1st half) into same slot -> 16 LDS reads + 16 MFMA.
// launch_bounds(512,1): never cap regs (LDS already limits to 1 block/CU).
__global__ __launch_bounds__(512, 1) void gemm_xw_mfma(
    const float* __restrict__ Xsrc, const float* __restrict__ Xdst,
    const unsigned short* __restrict__ Wt, const float* __restrict__ b1,
    unsigned short* __restrict__ U, unsigned short* __restrict__ V)
{
    const int zz = blockIdx.z;
    const float* X = zz ? Xdst : Xsrc;
    const unsigned short* Wz = Wt + (size_t)zz * 256 * 256;
    unsigned short* C = zz ? V : U;

    __shared__ __align__(16) unsigned short Bs[256 * 256];   // 128 KiB

    const int t = threadIdx.x;
    // Stage B once: 8192 16B-chunks / 512 threads = 16 each.
#pragma unroll
    for (int i = 0; i < 16; i++) {
        int s = t + (i << 9);
        int n = s >> 5, c = s & 31;
        *(int4*)(Bs + n * 256 + ((c ^ (n & 7)) << 3)) =
            *(const int4*)(Wz + (size_t)n * 256 + (c << 3));
    }
    __syncthreads();        // the only barrier in this kernel

    const int w = t >> 6, lane = t & 63;
    const int quad = lane >> 4, l16 = lane & 15;
    const int r7 = l16 & 7;
    const unsigned short* Bl = Bs + l16 * 256;

    const int wid = w * GBLK + blockIdx.x;   // wave-major remainder spread

    // Rolling 4-slot prefetch ring: slot s holds fp32 for one kk (2 float4).
    float4 P[8];
    const float* ApCur = X + ((size_t)((wid << 4) + l16)) * D_IN + (quad << 3);
    int gn = wid + GSTRIDE; if (gn >= NGROUPS) gn = wid;     // clamp (harmless)
    const float* ApNext = X + ((size_t)((gn << 4) + l16)) * D_IN + (quad << 3);
#pragma unroll
    for (int s = 0; s < 4; s++) {
        P[2 * s]     = *(const float4*)(ApCur + s * 32);
        P[2 * s + 1] = *(const float4*)(ApCur + s * 32 + 4);
    }

#pragma unroll 1
    for (int g = wid; g < NGROUPS; g += GSTRIDE) {
        float4v acc[16];
#pragma unroll
        for (int i = 0; i < 16; i++) acc[i] = (float4v){0.f, 0.f, 0.f, 0.f};

#pragma unroll
        for (int kk = 0; kk < 8; kk++) {
            const int sl = kk & 3;
            // 1) Convert slot (loaded 4 kk-blocks ago -> latency covered).
            float4 a0 = P[2 * sl], a1 = P[2 * sl + 1];
            short8 af;
            af[0] = (short)f32_to_bf16_rne(a0.x);
            af[1] = (short)f32_to_bf16_rne(a0.y);
            af[2] = (short)f32_to_bf16_rne(a0.z);
            af[3] = (short)f32_to_bf16_rne(a0.w);
            af[4] = (short)f32_to_bf16_rne(a1.x);
            af[5] = (short)f32_to_bf16_rne(a1.y);
            af[6] = (short)f32_to_bf16_rne(a1.z);
            af[7] = (short)f32_to_bf16_rne(a1.w);
            // 2) Refill slot with kk+4: this group's 2nd half or next group's 1st.
            const float* Lp = (kk < 4) ? (ApCur + (kk + 4) * 32)
                                       : (ApNext + (kk - 4) * 32);
            P[2 * sl]     = *(const float4*)(Lp);
            P[2 * sl + 1] = *(const float4*)(Lp + 4);
            // 3) 16 LDS bf-reads + 16 MFMA (no VMEM dependency).
            const int cs = (((kk << 2) + quad) ^ r7) << 3;
#pragma unroll
            for (int tt = 0; tt < 16; tt++) {
                short8 bf = *(const short8*)(Bl + tt * 4096 + cs);
                // swapped operands: D = (Wt-tile) x (X-tile): lane owns output
                // ROW m = l16; output cols n = tt*16 + quad*4 + r.
                acc[tt] = __builtin_amdgcn_mfma_f32_16x16x32_bf16(bf, af, acc[tt], 0, 0, 0);
            }
        }

        // Epilogue: lane writes its own row: 16 x 8B stores, 32B/row/instr.
        const int row = (g << 4) + l16;
        unsigned short* Crow = C + (size_t)row * HID + (quad << 2);
#pragma unroll
        for (int tt = 0; tt < 16; tt++) {
            float4v a = acc[tt];
            if (zz == 0) {
                float4 bb = *(const float4*)(b1 + tt * 16 + (quad << 2));
                a[0] += bb.x; a[1] += bb.y; a[2] += bb.z; a[3] += bb.w;
            }
            ushort4 pk;
            pk.x = f32_to_bf16_rne(a[0]);
            pk.y = f32_to_bf16_rne(a[1]);
            pk.z = f32_to_bf16_rne(a[2]);
            pk.w = f32_to_bf16_rne(a[3]);
            *(ushort4*)(Crow + tt * 16) = pk;
        }

        // Advance pipeline pointers: Cur <- Next, Next <- g + 2*GSTRIDE.
        ApCur = ApNext;
        int g2 = g + 2 * GSTRIDE;
        if (g2 >= NGROUPS) g2 = g;           // clamp to a valid row block
        ApNext = X + ((size_t)((g2 << 4) + l16)) * D_IN + (quad << 3);
    }
}

// -------- Phase 2: out[e] = relu(U[s]+V[d]) . W2 + b2   (b1 folded into U) --------
__global__ __launch_bounds__(256) void edge_score_bf16(
    const unsigned short* __restrict__ U, const unsigned short* __restrict__ V,
    const float* __restrict__ W2, const float* __restrict__ b2,
    const int* __restrict__ epos, const int* __restrict__ eneg,
    float* __restrict__ out)
{
    const int w = threadIdx.x >> 6, lane = threadIdx.x & 63;
    const int half = lane >> 5, hl = lane & 31;
    const int ebase = blockIdx.x * 64 + w * 16;     // 16 edges per wave

    const int* ei = (ebase < NEDGE) ? epos : eneg;
    const int eb2 = (ebase < NEDGE) ? ebase : ebase - NEDGE;

    int sidx[8], didx[8];
#pragma unroll
    for (int p = 0; p < 8; p++) {
        int e = eb2 + 2 * p + half;
        sidx[p] = ei[e];
        didx[p] = ei[NEDGE + e];
    }
    ushort8 uu[8], vv[8];
#pragma unroll
    for (int p = 0; p < 8; p++)
        uu[p] = *(const ushort8*)(U + (size_t)sidx[p] * HID + hl * 8);
#pragma unroll
    for (int p = 0; p < 8; p++)
        vv[p] = *(const ushort8*)(V + (size_t)didx[p] * HID + hl * 8);

    float w2r[8];
    *(float4*)&w2r[0] = *(const float4*)(W2 + hl * 8);
    *(float4*)&w2r[4] = *(const float4*)(W2 + hl * 8 + 4);
    const float bb2 = b2[0];

#pragma unroll
    for (int p = 0; p < 8; p++) {
        float s = 0.f;
#pragma unroll
        for (int q = 0; q < 8; q++)
            s += fmaxf(bf16_to_f32(uu[p][q]) + bf16_to_f32(vv[p][q]), 0.f) * w2r[q];
#pragma unroll
        for (int off = 16; off; off >>= 1)     // xor within each 32-lane half
            s += __shfl_xor(s, off, 64);
        if (hl == 0) out[ebase + 2 * p + half] = s + bb2;
    }
}

// -------- Fallback (ws too small): direct per-edge MLP --------
__global__ __launch_bounds__(256) void edge_score_direct(
    const float* __restrict__ xs_, const float* __restrict__ xd_,
    const float* __restrict__ W1, const float* __restrict__ b1,
    const float* __restrict__ W2, const float* __restrict__ b2,
    const int* __restrict__ epos, const int* __restrict__ eneg,
    float* __restrict__ out)
{
    __shared__ float xrow[2 * D_IN];
    __shared__ float red[256];
    const int e = blockIdx.x;
    const int* ei = (e < NEDGE) ? epos : eneg;
    const int e2  = (e < NEDGE) ? e : e - NEDGE;
    const int s = ei[e2];
    const int d = ei[NEDGE + e2];
    const int t = threadIdx.x;

    xrow[t]        = xs_[(size_t)s * D_IN + t];
    xrow[D_IN + t] = xd_[(size_t)d * D_IN + t];
    __syncthreads();

    float acc = b1[t];
    for (int k = 0; k < 2 * D_IN; k++)
        acc += xrow[k] * W1[(size_t)k * HID + t];
    acc = fmaxf(acc, 0.f);
    red[t] = acc * W2[t];
    __syncthreads();
    for (int st = 128; st; st >>= 1) {
        if (t < st) red[t] += red[t + st];
        __syncthreads();
    }
    if (t == 0) out[e] = red[0] + b2[0];
}

extern "C" void kernel_launch(void* const* d_in, const int* in_sizes, int n_in,
                              void* d_out, int out_size, void* d_ws, size_t ws_size,
                              hipStream_t stream) {
    const float* x_src = (const float*)d_in[0];
    const float* x_dst = (const float*)d_in[1];
    const float* W1    = (const float*)d_in[2];
    const float* b1    = (const float*)d_in[3];
    const float* W2    = (const float*)d_in[4];
    const float* b2    = (const float*)d_in[5];
    const int*   epos  = (const int*)d_in[6];
    const int*   eneg  = (const int*)d_in[7];
    float* out = (float*)d_out;

    const size_t uv   = (size_t)NNODES * HID;
    const size_t need = (2 * uv + 2 * 256 * 256) * sizeof(unsigned short);
    if (ws_size >= need) {
        unsigned short* U  = (unsigned short*)d_ws;
        unsigned short* V  = U + uv;
        unsigned short* Wt = V + uv;
        convert_w<<<dim3(4, 4, 2), 256, 0, stream>>>(W1, Wt);
        gemm_xw_mfma<<<dim3(GBLK, 1, 2), 512, 0, stream>>>(x_src, x_dst, Wt, b1, U, V);
        edge_score_bf16<<<(2 * NEDGE) / 64, 256, 0, stream>>>(U, V, W2, b2, epos, eneg, out);
    } else {
        edge_score_direct<<<2 * NEDGE, 256, 0, stream>>>(x_src, x_dst, W1, b1, W2, b2, epos, eneg, out);
    }
}

// Round 4
// 607.940 us; speedup vs baseline: 1.1118x; 1.0777x over previous
//
#include <hip/hip_runtime.h>

#define D_IN   256
#define HID    256
#define NNODES 100000
#define NEDGE  262144
#define NGROUPS 6250        // 100000 / 16 rows per MFMA m-group (exact)
#define GBLK   128          // blocks per z (x2 z = 256 blocks = 1/CU)
#define NPAIR  8            // wave-pairs per block (16 waves)
#define GSTRIDE (GBLK * NPAIR) // 1024 wave-pairs per z

typedef short short8            __attribute__((ext_vector_type(8)));
typedef float float4v           __attribute__((ext_vector_type(4)));
typedef unsigned short ushort8  __attribute__((ext_vector_type(8)));

__device__ __forceinline__ unsigned short f32_to_bf16_rne(float f) {
    unsigned int u = __float_as_uint(f);
    unsigned int r = u + 0x7FFFu + ((u >> 16) & 1u);
    return (unsigned short)(r >> 16);
}
__device__ __forceinline__ float bf16_to_f32(unsigned short h) {
    return __uint_as_float(((unsigned int)h) << 16);
}

// -------- W1 (fp32 [2*256][256], k-major) -> Wt (bf16 [z][n][k]) — LDS tile transpose --------
__global__ __launch_bounds__(256) void convert_w(
    const float* __restrict__ W1, unsigned short* __restrict__ Wt)
{
    __shared__ float tile[64][65];
    const int z = blockIdx.z, kb = blockIdx.x * 64, nb = blockIdx.y * 64;
    const int t = threadIdx.x;
    const int g = t >> 6, c = t & 63;
#pragma unroll
    for (int r = 0; r < 16; r++) {
        int kl = g * 16 + r;
        tile[kl][c] = W1[((size_t)(z * 256 + kb + kl)) * 256 + nb + c];
    }
    __syncthreads();
#pragma unroll
    for (int r = 0; r < 16; r++) {
        int nl = g * 16 + r;
        Wt[((size_t)(z * 256 + nb + nl)) * 256 + kb + c] = f32_to_bf16_rne(tile[c][nl]);
    }
}

// -------- Phase 1: U = Xsrc@W1_top + b1 (bf16), V = Xdst@W1_bot (bf16) --------
// Round-7 structure. LESSONS: (r4, 105us) 1-deep prefetch at 16 waves exposes
// ~500cyc/kk; (r5/r6, 460us) ANY structure at 512thr/8waves gets capped at 128
// arch VGPRs and spills ~75 regs/iter -> 900MB scratch. Only known-safe shape:
// 1024 thr, 16 waves, total regs (VGPR+AGPR) <= 128.
// FIX: halve the accumulator instead of the ring. Each 16-row group's N=256 is
// split across a WAVE PAIR (nh = w&1 owns 128 cols): acc 64->32 AGPR, freeing
// 32 regs for a 4-deep prefetch ring (P[8] float4). Total ~95 regs: fits.
// Pair waves load identical A rows concurrently -> 2nd read is an L1/L2 hit,
// HBM traffic unchanged. Ring rolls across group boundaries: no head bubble.
__global__ __launch_bounds__(1024, 4) void gemm_xw_mfma(
    const float* __restrict__ Xsrc, const float* __restrict__ Xdst,
    const unsigned short* __restrict__ Wt, const float* __restrict__ b1,
    unsigned short* __restrict__ U, unsigned short* __restrict__ V)
{
    const int zz = blockIdx.z;
    const float* X = zz ? Xdst : Xsrc;
    const unsigned short* Wz = Wt + (size_t)zz * 256 * 256;
    unsigned short* C = zz ? V : U;

    __shared__ __align__(16) unsigned short Bs[256 * 256];   // 128 KiB

    const int t = threadIdx.x;
    // Stage B once: 8192 16B-chunks / 1024 threads = 8 each; XOR-swizzled.
#pragma unroll
    for (int i = 0; i < 8; i++) {
        int s = t + (i << 10);
        int n = s >> 5, c = s & 31;
        *(int4*)(Bs + n * 256 + ((c ^ (n & 7)) << 3)) =
            *(const int4*)(Wz + (size_t)n * 256 + (c << 3));
    }
    __syncthreads();        // the only barrier in this kernel

    const int w = t >> 6, lane = t & 63;
    const int quad = lane >> 4, l16 = lane & 15;
    const int r7 = l16 & 7;
    const int nh = w & 1;                    // which 128-col half of N
    const int gw = w >> 1;                   // pair index within block (0..7)
    const unsigned short* Bl = Bs + (nh * 128 + l16) * 256;

    const int wid = gw * GBLK + blockIdx.x;  // pair-major remainder spread

    // 4-deep rolling prefetch ring: slot s = one kk (2 float4 = 8 regs).
    float4 P[8];
    const float* ApCur = X + ((size_t)((wid << 4) + l16)) * D_IN + (quad << 3);
    const float* ApNext = X + ((size_t)(((wid + GSTRIDE) < NGROUPS ?
                          (wid + GSTRIDE) : wid) << 4) + l16) * D_IN + (quad << 3);
#pragma unroll
    for (int s = 0; s < 4; s++) {
        P[2 * s]     = *(const float4*)(ApCur + s * 32);
        P[2 * s + 1] = *(const float4*)(ApCur + s * 32 + 4);
    }

#pragma unroll 1
    for (int g = wid; g < NGROUPS; g += GSTRIDE) {
        float4v acc[8];
#pragma unroll
        for (int i = 0; i < 8; i++) acc[i] = (float4v){0.f, 0.f, 0.f, 0.f};

#pragma unroll
        for (int kk = 0; kk < 8; kk++) {
            const int sl = kk & 3;
            // 1) Convert slot (loaded 4 kk-blocks ago -> latency covered).
            float4 a0 = P[2 * sl], a1 = P[2 * sl + 1];
            short8 af;
            af[0] = (short)f32_to_bf16_rne(a0.x);
            af[1] = (short)f32_to_bf16_rne(a0.y);
            af[2] = (short)f32_to_bf16_rne(a0.z);
            af[3] = (short)f32_to_bf16_rne(a0.w);
            af[4] = (short)f32_to_bf16_rne(a1.x);
            af[5] = (short)f32_to_bf16_rne(a1.y);
            af[6] = (short)f32_to_bf16_rne(a1.z);
            af[7] = (short)f32_to_bf16_rne(a1.w);
            // 2) Refill slot with kk+4 (this group's 2nd half / next group's 1st).
            const float* Lp = (kk < 4) ? (ApCur + (kk + 4) * 32)
                                       : (ApNext + (kk - 4) * 32);
            P[2 * sl]     = *(const float4*)(Lp);
            P[2 * sl + 1] = *(const float4*)(Lp + 4);
            // 3) 8 LDS bf-reads + 8 MFMA for this wave's 128-col half.
            const int cs = (((kk << 2) + quad) ^ r7) << 3;
#pragma unroll
            for (int tt = 0; tt < 8; tt++) {
                short8 bf = *(const short8*)(Bl + tt * 4096 + cs);
                // swapped operands: D = (Wt-half) x (X-rows): lane owns output
                // ROW m = l16; output cols n = nh*128 + tt*16 + quad*4 + r.
                acc[tt] = __builtin_amdgcn_mfma_f32_16x16x32_bf16(bf, af, acc[tt], 0, 0, 0);
            }
        }

        // Epilogue: lane writes its half-row: 8 x 8B stores.
        const int row = (g << 4) + l16;
        unsigned short* Crow = C + (size_t)row * HID + nh * 128 + (quad << 2);
#pragma unroll
        for (int tt = 0; tt < 8; tt++) {
            float4v a = acc[tt];
            if (zz == 0) {
                float4 bb = *(const float4*)(b1 + nh * 128 + tt * 16 + (quad << 2));
                a[0] += bb.x; a[1] += bb.y; a[2] += bb.z; a[3] += bb.w;
            }
            ushort4 pk;
            pk.x = f32_to_bf16_rne(a[0]);
            pk.y = f32_to_bf16_rne(a[1]);
            pk.z = f32_to_bf16_rne(a[2]);
            pk.w = f32_to_bf16_rne(a[3]);
            *(ushort4*)(Crow + tt * 16) = pk;
        }

        // Advance pipeline pointers.
        ApCur = ApNext;
        int g2 = g + 2 * GSTRIDE;
        if (g2 >= NGROUPS) g2 = g;           // clamp to valid rows (tail only)
        ApNext = X + ((size_t)(g2 << 4) + l16) * D_IN + (quad << 3);
    }
}

// -------- Phase 2: out[e] = relu(U[s]+V[d]) . W2 + b2   (b1 folded into U) --------
__global__ __launch_bounds__(256) void edge_score_bf16(
    const unsigned short* __restrict__ U, const unsigned short* __restrict__ V,
    const float* __restrict__ W2, const float* __restrict__ b2,
    const int* __restrict__ epos, const int* __restrict__ eneg,
    float* __restrict__ out)
{
    const int w = threadIdx.x >> 6, lane = threadIdx.x & 63;
    const int half = lane >> 5, hl = lane & 31;
    const int ebase = blockIdx.x * 64 + w * 16;     // 16 edges per wave

    const int* ei = (ebase < NEDGE) ? epos : eneg;
    const int eb2 = (ebase < NEDGE) ? ebase : ebase - NEDGE;

    int sidx[8], didx[8];
#pragma unroll
    for (int p = 0; p < 8; p++) {
        int e = eb2 + 2 * p + half;
        sidx[p] = ei[e];
        didx[p] = ei[NEDGE + e];
    }
    ushort8 uu[8], vv[8];
#pragma unroll
    for (int p = 0; p < 8; p++)
        uu[p] = *(const ushort8*)(U + (size_t)sidx[p] * HID + hl * 8);
#pragma unroll
    for (int p = 0; p < 8; p++)
        vv[p] = *(const ushort8*)(V + (size_t)didx[p] * HID + hl * 8);

    float w2r[8];
    *(float4*)&w2r[0] = *(const float4*)(W2 + hl * 8);
    *(float4*)&w2r[4] = *(const float4*)(W2 + hl * 8 + 4);
    const float bb2 = b2[0];

#pragma unroll
    for (int p = 0; p < 8; p++) {
        float s = 0.f;
#pragma unroll
        for (int q = 0; q < 8; q++)
            s += fmaxf(bf16_to_f32(uu[p][q]) + bf16_to_f32(vv[p][q]), 0.f) * w2r[q];
#pragma unroll
        for (int off = 16; off; off >>= 1)     // xor within each 32-lane half
            s += __shfl_xor(s, off, 64);
        if (hl == 0) out[ebase + 2 * p + half] = s + bb2;
    }
}

// -------- Fallback (ws too small): direct per-edge MLP --------
__global__ __launch_bounds__(256) void edge_score_direct(
    const float* __restrict__ xs_, const float* __restrict__ xd_,
    const float* __restrict__ W1, const float* __restrict__ b1,
    const float* __restrict__ W2, const float* __restrict__ b2,
    const int* __restrict__ epos, const int* __restrict__ eneg,
    float* __restrict__ out)
{
    __shared__ float xrow[2 * D_IN];
    __shared__ float red[256];
    const int e = blockIdx.x;
    const int* ei = (e < NEDGE) ? epos : eneg;
    const int e2  = (e < NEDGE) ? e : e - NEDGE;
    const int s = ei[e2];
    const int d = ei[NEDGE + e2];
    const int t = threadIdx.x;

    xrow[t]        = xs_[(size_t)s * D_IN + t];
    xrow[D_IN + t] = xd_[(size_t)d * D_IN + t];
    __syncthreads();

    float acc = b1[t];
    for (int k = 0; k < 2 * D_IN; k++)
        acc += xrow[k] * W1[(size_t)k * HID + t];
    acc = fmaxf(acc, 0.f);
    red[t] = acc * W2[t];
    __syncthreads();
    for (int st = 128; st; st >>= 1) {
        if (t < st) red[t] += red[t + st];
        __syncthreads();
    }
    if (t == 0) out[e] = red[0] + b2[0];
}

extern "C" void kernel_launch(void* const* d_in, const int* in_sizes, int n_in,
                              void* d_out, int out_size, void* d_ws, size_t ws_size,
                              hipStream_t stream) {
    const float* x_src = (const float*)d_in[0];
    const float* x_dst = (const float*)d_in[1];
    const float* W1    = (const float*)d_in[2];
    const float* b1    = (const float*)d_in[3];
    const float* W2    = (const float*)d_in[4];
    const float* b2    = (const float*)d_in[5];
    const int*   epos  = (const int*)d_in[6];
    const int*   eneg  = (const int*)d_in[7];
    float* out = (float*)d_out;

    const size_t uv   = (size_t)NNODES * HID;
    const size_t need = (2 * uv + 2 * 256 * 256) * sizeof(unsigned short);
    if (ws_size >= need) {
        unsigned short* U  = (unsigned short*)d_ws;
        unsigned short* V  = U + uv;
        unsigned short* Wt = V + uv;
        convert_w<<<dim3(4, 4, 2), 256, 0, stream>>>(W1, Wt);
        gemm_xw_mfma<<<dim3(GBLK, 1, 2), 1024, 0, stream>>>(x_src, x_dst, Wt, b1, U, V);
        edge_score_bf16<<<(2 * NEDGE) / 64, 256, 0, stream>>>(U, V, W2, b2, epos, eneg, out);
    } else {
        edge_score_direct<<<2 * NEDGE, 256, 0, stream>>>(x_src, x_dst, W1, b1, W2, b2, epos, eneg, out);
    }
}